// Round 1
// baseline (607.443 us; speedup 1.0000x reference)
//
#include <hip/hip_runtime.h>

// ---------------- edge-index dtype detection ----------------
// int64 node indices < 2^31 have zero high words (little-endian). For real
// int32 index data, 64 consecutive odd words all being zero is impossible.
__global__ void k_detect(const int* __restrict__ ei32, int* __restrict__ flag) {
  if (threadIdx.x == 0) {
    int z = 1;
    for (int k = 0; k < 64; ++k)
      if (ei32[2 * k + 1] != 0) { z = 0; break; }
    flag[0] = z;  // 1 => int64, 0 => int32
  }
}

__device__ __forceinline__ int edge_at(const void* ei, int is64, long long pos) {
  return is64 ? (int)((const long long*)ei)[pos] : ((const int*)ei)[pos];
}

__global__ void k_init(int* __restrict__ deg, int* __restrict__ cur, int n) {
  int i = blockIdx.x * blockDim.x + threadIdx.x;
  if (i < n) { deg[i] = 2; cur[i] = 0; }  // deg starts at 2 (double self-loops)
}

__global__ void k_count(const void* __restrict__ ei, const int* __restrict__ flag,
                        int E, int* __restrict__ deg) {
  int e = blockIdx.x * blockDim.x + threadIdx.x;
  if (e >= E) return;
  int is64 = flag[0];
  int c = edge_at(ei, is64, (long long)E + e);  // col = target
  atomicAdd(&deg[c], 1);
}

__global__ void k_dis(const int* __restrict__ deg, float* __restrict__ dis, int n) {
  int i = blockIdx.x * blockDim.x + threadIdx.x;
  if (i < n) dis[i] = rsqrtf((float)deg[i]);
}

// ---------------- exclusive scan of (deg-2) -> rowptr ----------------
__global__ void k_scanA(const int* __restrict__ deg, int* __restrict__ rowptr,
                        int* __restrict__ bsum, int n) {
  __shared__ int sh[256];
  int t = threadIdx.x;
  int base = blockIdx.x * 1024 + t * 4;
  int v[4]; int s = 0;
#pragma unroll
  for (int i = 0; i < 4; ++i) {
    int idx = base + i;
    int c = (idx < n) ? (deg[idx] - 2) : 0;
    v[i] = s; s += c;
  }
  sh[t] = s;
  __syncthreads();
  for (int off = 1; off < 256; off <<= 1) {
    int x = 0;
    if (t >= off) x = sh[t - off];
    __syncthreads();
    if (t >= off) sh[t] += x;
    __syncthreads();
  }
  int pre = (t > 0) ? sh[t - 1] : 0;
#pragma unroll
  for (int i = 0; i < 4; ++i) {
    int idx = base + i;
    if (idx < n) rowptr[idx] = pre + v[i];
  }
  if (t == 255) bsum[blockIdx.x] = sh[255];
}

__global__ void k_scanB(int* __restrict__ bsum, int nb) {
  if (threadIdx.x == 0) {
    int s = 0;
    for (int b = 0; b < nb; ++b) { int c = bsum[b]; bsum[b] = s; s += c; }
  }
}

__global__ void k_scanC(int* __restrict__ rowptr, const int* __restrict__ bsum,
                        int n, int E) {
  int i = blockIdx.x * blockDim.x + threadIdx.x;
  if (i < n) rowptr[i] += bsum[i >> 10];
  if (i == n - 1) rowptr[n] = E;
}

__global__ void k_fill(const void* __restrict__ ei, const int* __restrict__ flag, int E,
                       const float* __restrict__ dis, const int* __restrict__ rowptr,
                       int* __restrict__ cur, int* __restrict__ esrc,
                       float* __restrict__ enorm) {
  int e = blockIdx.x * blockDim.x + threadIdx.x;
  if (e >= E) return;
  int is64 = flag[0];
  int r = edge_at(ei, is64, e);
  int c = edge_at(ei, is64, (long long)E + e);
  int pos = rowptr[c] + atomicAdd(&cur[c], 1);
  esrc[pos] = r;
  enorm[pos] = dis[r] * dis[c];
}

// ---------------- fp32 GEMM: C[M x BN] = A[M x 128] * W[128 x BN] ----------------
// 256 threads, BM=128, thread tile 8 rows x (BN/64 groups of 4 cols).
template <int BN>
__global__ __launch_bounds__(256) void k_gemm(const float* __restrict__ A,
                                              const float* __restrict__ W,
                                              float* __restrict__ C, int M) {
  constexpr int NG = BN / 64;
  __shared__ float As[16][132];  // transposed A tile: As[k][row], padded
  __shared__ float Ws[16][BN];
  int t = threadIdx.x;
  int tc = t & 15, tr = t >> 4;
  int row0 = blockIdx.x * 128;
  float acc[8][NG][4];
#pragma unroll
  for (int i = 0; i < 8; ++i)
#pragma unroll
    for (int g = 0; g < NG; ++g)
#pragma unroll
      for (int j = 0; j < 4; ++j) acc[i][g][j] = 0.f;

  for (int k0 = 0; k0 < 128; k0 += 16) {
#pragma unroll
    for (int i = 0; i < 2; ++i) {
      int idx = t * 2 + i;
      int r = idx >> 2, q = idx & 3;
      int gr = row0 + r;
      float4 v = make_float4(0.f, 0.f, 0.f, 0.f);
      if (gr < M) v = *(const float4*)&A[(long long)gr * 128 + k0 + q * 4];
      As[q * 4 + 0][r] = v.x; As[q * 4 + 1][r] = v.y;
      As[q * 4 + 2][r] = v.z; As[q * 4 + 3][r] = v.w;
    }
#pragma unroll
    for (int i = 0; i < BN / 64; ++i) {
      int idx = t + i * 256;
      int k = idx / (BN / 4), c4 = idx % (BN / 4);
      *(float4*)&Ws[k][c4 * 4] = *(const float4*)&W[(long long)(k0 + k) * BN + c4 * 4];
    }
    __syncthreads();
#pragma unroll
    for (int k = 0; k < 16; ++k) {
      float a[8], b[NG][4];
      *(float4*)&a[0] = *(const float4*)&As[k][tr * 8];
      *(float4*)&a[4] = *(const float4*)&As[k][tr * 8 + 4];
#pragma unroll
      for (int g = 0; g < NG; ++g)
        *(float4*)&b[g][0] = *(const float4*)&Ws[k][g * 64 + tc * 4];
#pragma unroll
      for (int i = 0; i < 8; ++i)
#pragma unroll
        for (int g = 0; g < NG; ++g)
#pragma unroll
          for (int j = 0; j < 4; ++j)
            acc[i][g][j] = fmaf(a[i], b[g][j], acc[i][g][j]);
    }
    __syncthreads();
  }
#pragma unroll
  for (int i = 0; i < 8; ++i) {
    int gr = row0 + tr * 8 + i;
    if (gr < M) {
#pragma unroll
      for (int g = 0; g < NG; ++g)
        *(float4*)&C[(long long)gr * BN + g * 64 + tc * 4] = *(const float4*)&acc[i][g][0];
    }
  }
}

// ---------------- gather (A-hat propagate), one wave per node ----------------
template <int D, bool RELU>
__global__ __launch_bounds__(256) void k_gather(const float* __restrict__ t,
    const float* __restrict__ bias, const int* __restrict__ rowptr,
    const int* __restrict__ esrc, const float* __restrict__ enorm,
    const float* __restrict__ dis, float* __restrict__ o, int n) {
  int gw = (int)((blockIdx.x * blockDim.x + threadIdx.x) >> 6);
  int lane = threadIdx.x & 63;
  int nw = (int)((gridDim.x * blockDim.x) >> 6);
  for (int v = gw; v < n; v += nw) {
    float d = dis[v];
    float s = 2.f * d * d;  // two self-loops, norm = dis^2 each
    int beg = rowptr[v], end = rowptr[v + 1];
    if (D == 128) {
      int f = lane * 2;
      float2 xv = *(const float2*)&t[(long long)v * 128 + f];
      float a0 = s * xv.x, a1 = s * xv.y;
      int e = beg;
      for (; e + 1 < end; e += 2) {
        int s0 = esrc[e], s1 = esrc[e + 1];
        float n0 = enorm[e], n1 = enorm[e + 1];
        float2 x0 = *(const float2*)&t[(long long)s0 * 128 + f];
        float2 x1 = *(const float2*)&t[(long long)s1 * 128 + f];
        a0 = fmaf(n0, x0.x, a0); a1 = fmaf(n0, x0.y, a1);
        a0 = fmaf(n1, x1.x, a0); a1 = fmaf(n1, x1.y, a1);
      }
      if (e < end) {
        int s0 = esrc[e]; float n0 = enorm[e];
        float2 x0 = *(const float2*)&t[(long long)s0 * 128 + f];
        a0 = fmaf(n0, x0.x, a0); a1 = fmaf(n0, x0.y, a1);
      }
      a0 += bias[f]; a1 += bias[f + 1];
      if (RELU) { a0 = fmaxf(a0, 0.f); a1 = fmaxf(a1, 0.f); }
      *(float2*)&o[(long long)v * 128 + f] = make_float2(a0, a1);
    } else {
      int f = lane;
      float a0 = s * t[(long long)v * 64 + f];
      int e = beg;
      for (; e + 1 < end; e += 2) {
        int s0 = esrc[e], s1 = esrc[e + 1];
        float n0 = enorm[e], n1 = enorm[e + 1];
        float x0 = t[(long long)s0 * 64 + f];
        float x1 = t[(long long)s1 * 64 + f];
        a0 = fmaf(n0, x0, a0);
        a0 = fmaf(n1, x1, a0);
      }
      if (e < end) a0 = fmaf(enorm[e], t[(long long)esrc[e] * 64 + f], a0);
      a0 += bias[f];
      o[(long long)v * 64 + f] = a0;
    }
  }
}

extern "C" void kernel_launch(void* const* d_in, const int* in_sizes, int n_in,
                              void* d_out, int out_size, void* d_ws, size_t ws_size,
                              hipStream_t stream) {
  const float* x  = (const float*)d_in[0];
  const void*  ei = d_in[1];
  const float* W1 = (const float*)d_in[2];
  const float* b1 = (const float*)d_in[3];
  const float* W2 = (const float*)d_in[4];
  const float* b2 = (const float*)d_in[5];
  const int N = in_sizes[0] / 128;
  const int E = in_sizes[1] / 2;
  float* out = (float*)d_out;

  // workspace carve-up (~117 MB total)
  size_t off = 0;
  auto alloc = [&](size_t bytes) -> void* {
    void* p = (char*)d_ws + off;
    off += (bytes + 255) & ~(size_t)255;
    return p;
  };
  int*   flag   = (int*)alloc(4);
  int*   deg    = (int*)alloc((size_t)N * 4);
  int*   cur    = (int*)alloc((size_t)N * 4);
  float* dis    = (float*)alloc((size_t)N * 4);
  int*   rowptr = (int*)alloc(((size_t)N + 1) * 4);
  int*   bsum   = (int*)alloc(4096);
  int*   esrc   = (int*)alloc((size_t)E * 4);
  float* enorm  = (float*)alloc((size_t)E * 4);
  float* t1     = (float*)alloc((size_t)N * 128 * 4);
  float* z1     = (float*)alloc((size_t)N * 128 * 4);
  float* t2     = t1;  // t1 is dead once gather1 has produced z1

  int nb = (N + 1023) / 1024;

  k_detect<<<1, 64, 0, stream>>>((const int*)ei, flag);
  k_init<<<(N + 255) / 256, 256, 0, stream>>>(deg, cur, N);
  k_count<<<(E + 255) / 256, 256, 0, stream>>>(ei, flag, E, deg);
  k_dis<<<(N + 255) / 256, 256, 0, stream>>>(deg, dis, N);
  k_scanA<<<nb, 256, 0, stream>>>(deg, rowptr, bsum, N);
  k_scanB<<<1, 64, 0, stream>>>(bsum, nb);
  k_scanC<<<(N + 255) / 256, 256, 0, stream>>>(rowptr, bsum, N, E);
  k_fill<<<(E + 255) / 256, 256, 0, stream>>>(ei, flag, E, dis, rowptr, cur, esrc, enorm);

  // layer 1: t1 = x @ W1 ; z1 = relu(Ahat t1 + b1)
  k_gemm<128><<<(N + 127) / 128, 256, 0, stream>>>(x, W1, t1, N);
  k_gather<128, true><<<1024, 256, 0, stream>>>(t1, b1, rowptr, esrc, enorm, dis, z1, N);
  // layer 2: t2 = z1 @ W2 ; out = Ahat t2 + b2
  k_gemm<64><<<(N + 127) / 128, 256, 0, stream>>>(z1, W2, t2, N);
  k_gather<64, false><<<1024, 256, 0, stream>>>(t2, b2, rowptr, esrc, enorm, dis, out, N);
}

// Round 2
// 381.545 us; speedup vs baseline: 1.5921x; 1.5921x over previous
//
#include <hip/hip_runtime.h>
#include <hip/hip_fp16.h>

struct h4 { __half2 a, b; };  // 4 contiguous halves, 8 B store

// ---------------- edge-index dtype detection ----------------
// int64 node indices < 2^31 have zero high words (little-endian). For real
// int32 index data, 64 consecutive odd words all being zero is impossible.
__global__ void k_detect(const int* __restrict__ ei32, int* __restrict__ flag) {
  if (threadIdx.x == 0) {
    int z = 1;
    for (int k = 0; k < 64; ++k)
      if (ei32[2 * k + 1] != 0) { z = 0; break; }
    flag[0] = z;  // 1 => int64, 0 => int32
  }
}

__device__ __forceinline__ int edge_at(const void* ei, int is64, long long pos) {
  return is64 ? (int)((const long long*)ei)[pos] : ((const int*)ei)[pos];
}

__global__ void k_init(int* __restrict__ deg, int* __restrict__ cur, int n) {
  int i = blockIdx.x * blockDim.x + threadIdx.x;
  if (i < n) { deg[i] = 2; cur[i] = 0; }  // deg starts at 2 (double self-loops)
}

__global__ void k_count(const void* __restrict__ ei, const int* __restrict__ flag,
                        int E, int* __restrict__ deg) {
  int e = blockIdx.x * blockDim.x + threadIdx.x;
  if (e >= E) return;
  int is64 = flag[0];
  int c = edge_at(ei, is64, (long long)E + e);  // col = target
  atomicAdd(&deg[c], 1);
}

__global__ void k_dis(const int* __restrict__ deg, float* __restrict__ dis, int n) {
  int i = blockIdx.x * blockDim.x + threadIdx.x;
  if (i < n) dis[i] = rsqrtf((float)deg[i]);
}

// ---------------- exclusive scan of (deg-2) -> rowptr ----------------
__global__ void k_scanA(const int* __restrict__ deg, int* __restrict__ rowptr,
                        int* __restrict__ bsum, int n) {
  __shared__ int sh[256];
  int t = threadIdx.x;
  int base = blockIdx.x * 1024 + t * 4;
  int v[4]; int s = 0;
#pragma unroll
  for (int i = 0; i < 4; ++i) {
    int idx = base + i;
    int c = (idx < n) ? (deg[idx] - 2) : 0;
    v[i] = s; s += c;
  }
  sh[t] = s;
  __syncthreads();
  for (int off = 1; off < 256; off <<= 1) {
    int x = 0;
    if (t >= off) x = sh[t - off];
    __syncthreads();
    if (t >= off) sh[t] += x;
    __syncthreads();
  }
  int pre = (t > 0) ? sh[t - 1] : 0;
#pragma unroll
  for (int i = 0; i < 4; ++i) {
    int idx = base + i;
    if (idx < n) rowptr[idx] = pre + v[i];
  }
  if (t == 255) bsum[blockIdx.x] = sh[255];
}

__global__ void k_scanB(int* __restrict__ bsum, int nb) {
  if (threadIdx.x == 0) {
    int s = 0;
    for (int b = 0; b < nb; ++b) { int c = bsum[b]; bsum[b] = s; s += c; }
  }
}

__global__ void k_scanC(int* __restrict__ rowptr, const int* __restrict__ bsum,
                        int n, int E) {
  int i = blockIdx.x * blockDim.x + threadIdx.x;
  if (i < n) rowptr[i] += bsum[i >> 10];
  if (i == n - 1) rowptr[n] = E;
}

__global__ void k_fill(const void* __restrict__ ei, const int* __restrict__ flag, int E,
                       const float* __restrict__ dis, const int* __restrict__ rowptr,
                       int* __restrict__ cur, int2* __restrict__ edges) {
  int e = blockIdx.x * blockDim.x + threadIdx.x;
  if (e >= E) return;
  int is64 = flag[0];
  int r = edge_at(ei, is64, e);
  int c = edge_at(ei, is64, (long long)E + e);
  int pos = rowptr[c] + atomicAdd(&cur[c], 1);
  int2 ed;
  ed.x = r;
  ed.y = __float_as_int(dis[r] * dis[c]);
  edges[pos] = ed;  // single 8 B store
}

// ---------------- fp32 GEMM: C[M x BN] = A[M x 128] * W[128 x BN] ----------------
// 256 threads, BM=128, thread tile 8 rows x (BN/64 groups of 4 cols).
// A is fp32 or fp16 (AHALF); C is written fp16.
template <int BN, bool AHALF>
__global__ __launch_bounds__(256) void k_gemm(const void* __restrict__ Av,
                                              const float* __restrict__ W,
                                              __half* __restrict__ C, int M) {
  constexpr int NG = BN / 64;
  __shared__ float As[16][132];  // transposed A tile: As[k][row], padded
  __shared__ float Ws[16][BN];
  int t = threadIdx.x;
  int tc = t & 15, tr = t >> 4;
  int row0 = blockIdx.x * 128;
  float acc[8][NG][4];
#pragma unroll
  for (int i = 0; i < 8; ++i)
#pragma unroll
    for (int g = 0; g < NG; ++g)
#pragma unroll
      for (int j = 0; j < 4; ++j) acc[i][g][j] = 0.f;

  for (int k0 = 0; k0 < 128; k0 += 16) {
#pragma unroll
    for (int i = 0; i < 2; ++i) {
      int idx = t * 2 + i;
      int r = idx >> 2, q = idx & 3;
      int gr = row0 + r;
      float4 v = make_float4(0.f, 0.f, 0.f, 0.f);
      if (gr < M) {
        if constexpr (AHALF) {
          const __half* A = (const __half*)Av;
          uint2 u = *(const uint2*)&A[(size_t)gr * 128 + k0 + q * 4];
          __half2 p0 = *(__half2*)&u.x, p1 = *(__half2*)&u.y;
          v = make_float4(__low2float(p0), __high2float(p0),
                          __low2float(p1), __high2float(p1));
        } else {
          v = *(const float4*)&((const float*)Av)[(size_t)gr * 128 + k0 + q * 4];
        }
      }
      As[q * 4 + 0][r] = v.x; As[q * 4 + 1][r] = v.y;
      As[q * 4 + 2][r] = v.z; As[q * 4 + 3][r] = v.w;
    }
#pragma unroll
    for (int i = 0; i < BN / 64; ++i) {
      int idx = t + i * 256;
      int k = idx / (BN / 4), c4 = idx % (BN / 4);
      *(float4*)&Ws[k][c4 * 4] = *(const float4*)&W[(long long)(k0 + k) * BN + c4 * 4];
    }
    __syncthreads();
#pragma unroll
    for (int k = 0; k < 16; ++k) {
      float a[8], b[NG][4];
      *(float4*)&a[0] = *(const float4*)&As[k][tr * 8];
      *(float4*)&a[4] = *(const float4*)&As[k][tr * 8 + 4];
#pragma unroll
      for (int g = 0; g < NG; ++g)
        *(float4*)&b[g][0] = *(const float4*)&Ws[k][g * 64 + tc * 4];
#pragma unroll
      for (int i = 0; i < 8; ++i)
#pragma unroll
        for (int g = 0; g < NG; ++g)
#pragma unroll
          for (int j = 0; j < 4; ++j)
            acc[i][g][j] = fmaf(a[i], b[g][j], acc[i][g][j]);
    }
    __syncthreads();
  }
#pragma unroll
  for (int i = 0; i < 8; ++i) {
    int gr = row0 + tr * 8 + i;
    if (gr < M) {
#pragma unroll
      for (int g = 0; g < NG; ++g) {
        h4 hh;
        hh.a = __floats2half2_rn(acc[i][g][0], acc[i][g][1]);
        hh.b = __floats2half2_rn(acc[i][g][2], acc[i][g][3]);
        *(h4*)&C[(size_t)gr * BN + g * 64 + tc * 4] = hh;
      }
    }
  }
}

// ---------------- gather (A-hat propagate), one wave per node ----------------
// D=128, fp16 in, fp16 out (+bias, relu). Lane covers 2 features.
__global__ __launch_bounds__(256) void k_gather128(const __half* __restrict__ t,
    const float* __restrict__ bias, const int* __restrict__ rowptr,
    const int2* __restrict__ edges, const float* __restrict__ dis,
    __half* __restrict__ o, int n) {
  int gw = (int)((blockIdx.x * blockDim.x + threadIdx.x) >> 6);
  int lane = threadIdx.x & 63;
  int nw = (int)((gridDim.x * blockDim.x) >> 6);
  int f = lane * 2;
  float bb0 = bias[f], bb1 = bias[f + 1];
  for (int v = gw; v < n; v += nw) {
    float d = dis[v];
    float s = 2.f * d * d;  // two self-loops, norm = dis^2 each
    __half2 xv = *(const __half2*)&t[(size_t)v * 128 + f];
    float a0 = s * __low2float(xv), a1 = s * __high2float(xv);
    int beg = rowptr[v], end = rowptr[v + 1];
    int e = beg;
    for (; e + 3 < end; e += 4) {
      int2 e0 = edges[e], e1 = edges[e + 1], e2 = edges[e + 2], e3 = edges[e + 3];
      __half2 x0 = *(const __half2*)&t[(size_t)e0.x * 128 + f];
      __half2 x1 = *(const __half2*)&t[(size_t)e1.x * 128 + f];
      __half2 x2 = *(const __half2*)&t[(size_t)e2.x * 128 + f];
      __half2 x3 = *(const __half2*)&t[(size_t)e3.x * 128 + f];
      float n0 = __int_as_float(e0.y), n1 = __int_as_float(e1.y);
      float n2 = __int_as_float(e2.y), n3 = __int_as_float(e3.y);
      a0 = fmaf(n0, __low2float(x0), a0); a1 = fmaf(n0, __high2float(x0), a1);
      a0 = fmaf(n1, __low2float(x1), a0); a1 = fmaf(n1, __high2float(x1), a1);
      a0 = fmaf(n2, __low2float(x2), a0); a1 = fmaf(n2, __high2float(x2), a1);
      a0 = fmaf(n3, __low2float(x3), a0); a1 = fmaf(n3, __high2float(x3), a1);
    }
    for (; e < end; ++e) {
      int2 e0 = edges[e];
      __half2 x0 = *(const __half2*)&t[(size_t)e0.x * 128 + f];
      float n0 = __int_as_float(e0.y);
      a0 = fmaf(n0, __low2float(x0), a0); a1 = fmaf(n0, __high2float(x0), a1);
    }
    a0 += bb0; a1 += bb1;
    a0 = fmaxf(a0, 0.f); a1 = fmaxf(a1, 0.f);  // layer 1 always relu
    *(__half2*)&o[(size_t)v * 128 + f] = __floats2half2_rn(a0, a1);
  }
}

// D=64, fp16 in, fp32 out (+bias, no relu). Lane covers 1 feature.
__global__ __launch_bounds__(256) void k_gather64(const __half* __restrict__ t,
    const float* __restrict__ bias, const int* __restrict__ rowptr,
    const int2* __restrict__ edges, const float* __restrict__ dis,
    float* __restrict__ o, int n) {
  int gw = (int)((blockIdx.x * blockDim.x + threadIdx.x) >> 6);
  int lane = threadIdx.x & 63;
  int nw = (int)((gridDim.x * blockDim.x) >> 6);
  int f = lane;
  float bb = bias[f];
  for (int v = gw; v < n; v += nw) {
    float d = dis[v];
    float s = 2.f * d * d;
    float a0 = s * __half2float(t[(size_t)v * 64 + f]);
    int beg = rowptr[v], end = rowptr[v + 1];
    int e = beg;
    for (; e + 3 < end; e += 4) {
      int2 e0 = edges[e], e1 = edges[e + 1], e2 = edges[e + 2], e3 = edges[e + 3];
      float x0 = __half2float(t[(size_t)e0.x * 64 + f]);
      float x1 = __half2float(t[(size_t)e1.x * 64 + f]);
      float x2 = __half2float(t[(size_t)e2.x * 64 + f]);
      float x3 = __half2float(t[(size_t)e3.x * 64 + f]);
      a0 = fmaf(__int_as_float(e0.y), x0, a0);
      a0 = fmaf(__int_as_float(e1.y), x1, a0);
      a0 = fmaf(__int_as_float(e2.y), x2, a0);
      a0 = fmaf(__int_as_float(e3.y), x3, a0);
    }
    for (; e < end; ++e)
      a0 = fmaf(__int_as_float(edges[e].y), __half2float(t[(size_t)edges[e].x * 64 + f]), a0);
    o[(size_t)v * 64 + f] = a0 + bb;
  }
}

extern "C" void kernel_launch(void* const* d_in, const int* in_sizes, int n_in,
                              void* d_out, int out_size, void* d_ws, size_t ws_size,
                              hipStream_t stream) {
  const float* x  = (const float*)d_in[0];
  const void*  ei = d_in[1];
  const float* W1 = (const float*)d_in[2];
  const float* b1 = (const float*)d_in[3];
  const float* W2 = (const float*)d_in[4];
  const float* b2 = (const float*)d_in[5];
  const int N = in_sizes[0] / 128;
  const int E = in_sizes[1] / 2;
  float* out = (float*)d_out;

  // workspace carve-up (~66 MB total)
  size_t off = 0;
  auto alloc = [&](size_t bytes) -> void* {
    void* p = (char*)d_ws + off;
    off += (bytes + 255) & ~(size_t)255;
    return p;
  };
  int*    flag   = (int*)alloc(4);
  int*    deg    = (int*)alloc((size_t)N * 4);
  int*    cur    = (int*)alloc((size_t)N * 4);
  float*  dis    = (float*)alloc((size_t)N * 4);
  int*    rowptr = (int*)alloc(((size_t)N + 1) * 4);
  int*    bsum   = (int*)alloc(4096);
  int2*   edges  = (int2*)alloc((size_t)E * 8);
  __half* t1     = (__half*)alloc((size_t)N * 128 * 2);
  __half* z1     = (__half*)alloc((size_t)N * 128 * 2);
  __half* t2     = t1;  // t1 is dead once gather1 has produced z1

  int nb = (N + 1023) / 1024;

  k_detect<<<1, 64, 0, stream>>>((const int*)ei, flag);
  k_init<<<(N + 255) / 256, 256, 0, stream>>>(deg, cur, N);
  k_count<<<(E + 255) / 256, 256, 0, stream>>>(ei, flag, E, deg);
  k_dis<<<(N + 255) / 256, 256, 0, stream>>>(deg, dis, N);
  k_scanA<<<nb, 256, 0, stream>>>(deg, rowptr, bsum, N);
  k_scanB<<<1, 64, 0, stream>>>(bsum, nb);
  k_scanC<<<(N + 255) / 256, 256, 0, stream>>>(rowptr, bsum, N, E);
  k_fill<<<(E + 255) / 256, 256, 0, stream>>>(ei, flag, E, dis, rowptr, cur, edges);

  // layer 1: t1 = x @ W1 (fp16 out); z1 = relu(Ahat t1 + b1) (fp16)
  k_gemm<128, false><<<(N + 127) / 128, 256, 0, stream>>>(x, W1, t1, N);
  k_gather128<<<2048, 256, 0, stream>>>(t1, b1, rowptr, edges, dis, z1, N);
  // layer 2: t2 = z1 @ W2 (fp16 out); out = Ahat t2 + b2 (fp32)
  k_gemm<64, true><<<(N + 127) / 128, 256, 0, stream>>>(z1, W2, t2, N);
  k_gather64<<<2048, 256, 0, stream>>>(t2, b2, rowptr, edges, dis, out, N);
}

// Round 3
// 290.725 us; speedup vs baseline: 2.0894x; 1.3124x over previous
//
#include <hip/hip_runtime.h>
#include <hip/hip_fp16.h>

#define NPB   512   // nodes per bucket (2^9)
#define NBMAX 256   // max buckets (N <= 131072)
#define CHUNK 4096  // edges staged per block iteration in k_fillB

struct h4 { __half2 a, b; };  // 4 contiguous halves, 8 B store

// ---------------- edge-index dtype detection + bucket-count zeroing --------
// int64 node indices < 2^31 have zero high words (little-endian). For real
// int32 index data, 64 consecutive odd words all being zero is impossible.
__global__ void k_detect(const int* __restrict__ ei32, int* __restrict__ flag,
                         int* __restrict__ bcnt, int nb) {
  int t = threadIdx.x;
  if (t < nb) bcnt[t] = 0;
  if (t == 0) {
    int z = 1;
    for (int k = 0; k < 64; ++k)
      if (ei32[2 * k + 1] != 0) { z = 0; break; }
    flag[0] = z;  // 1 => int64, 0 => int32
  }
}

__device__ __forceinline__ int edge_at(const void* ei, int is64, long long pos) {
  return is64 ? (int)((const long long*)ei)[pos] : ((const int*)ei)[pos];
}

// ---------------- phase A: per-bucket edge counts ----------------
__global__ __launch_bounds__(256) void k_bcount(const void* __restrict__ ei,
                                                const int* __restrict__ flag,
                                                int E, int* __restrict__ bcnt, int nb) {
  __shared__ int cnt[NBMAX];
  int t = threadIdx.x;
  cnt[t] = 0;
  __syncthreads();
  int is64 = flag[0];
  int stride = gridDim.x * blockDim.x;
  for (int e = blockIdx.x * blockDim.x + t; e < E; e += stride) {
    int c = edge_at(ei, is64, (long long)E + e);
    atomicAdd(&cnt[c >> 9], 1);
  }
  __syncthreads();
  if (t < nb && cnt[t]) atomicAdd(&bcnt[t], cnt[t]);
}

// ---------------- scan bucket counts -> bucket bases + cursors -------------
__global__ void k_bscan(const int* __restrict__ bcnt, int* __restrict__ bbase,
                        int* __restrict__ bcur, int* __restrict__ rowptr,
                        int nb, int N, int E) {
  __shared__ int sh[NBMAX];
  int t = threadIdx.x;
  sh[t] = (t < nb) ? bcnt[t] : 0;
  __syncthreads();
  for (int off = 1; off < NBMAX; off <<= 1) {
    int x = 0;
    if (t >= off) x = sh[t - off];
    __syncthreads();
    if (t >= off) sh[t] += x;
    __syncthreads();
  }
  int excl = t ? sh[t - 1] : 0;
  if (t < nb) { bbase[t] = excl; bcur[t] = excl; }
  if (t == 0) { bbase[nb] = E; rowptr[N] = E; }
}

// ---------------- phase B: bucket-partition edges with write combining -----
// Packs (c & 511) << 17 | r into 4 B; per-block LDS binning; per-bucket runs
// written contiguously (coalesced, full cache lines).
__global__ __launch_bounds__(256) void k_fillB(const void* __restrict__ ei,
                                               const int* __restrict__ flag, int E,
                                               int* __restrict__ bcur,
                                               int* __restrict__ tmp, int nb) {
  __shared__ int cntL[NBMAX], startL[NBMAX], curL[NBMAX], gofs[NBMAX];
  __shared__ int sh[NBMAX];
  __shared__ int stage[CHUNK];
  __shared__ unsigned char sbkt[CHUNK];
  int t = threadIdx.x;
  int is64 = flag[0];
  for (long long base = (long long)blockIdx.x * CHUNK; base < E;
       base += (long long)gridDim.x * CHUNK) {
    int m = (int)min((long long)CHUNK, (long long)E - base);
    cntL[t] = 0;
    __syncthreads();
    // pass 1: count buckets in this chunk
    for (int i = t; i < m; i += 256) {
      int c = edge_at(ei, is64, (long long)E + base + i);
      atomicAdd(&cntL[c >> 9], 1);
    }
    __syncthreads();
    sh[t] = cntL[t];
    __syncthreads();
    for (int off = 1; off < NBMAX; off <<= 1) {
      int x = 0;
      if (t >= off) x = sh[t - off];
      __syncthreads();
      if (t >= off) sh[t] += x;
      __syncthreads();
    }
    int excl = t ? sh[t - 1] : 0;
    startL[t] = excl;
    curL[t] = excl;
    if (t < nb && cntL[t] > 0) gofs[t] = atomicAdd(&bcur[t], cntL[t]);
    __syncthreads();
    // pass 2: place packed edges into LDS, sorted by bucket
    for (int i = t; i < m; i += 256) {
      int r = edge_at(ei, is64, base + i);
      int c = edge_at(ei, is64, (long long)E + base + i);
      int b = c >> 9;
      int p = atomicAdd(&curL[b], 1);
      stage[p] = ((c & 511) << 17) | r;
      sbkt[p] = (unsigned char)b;
    }
    __syncthreads();
    // pass 3: copy runs out contiguously
    for (int i = t; i < m; i += 256) {
      int b = sbkt[i];
      tmp[gofs[b] + (i - startL[b])] = stage[i];
    }
    __syncthreads();
  }
}

// ---------------- phase C: per-bucket CSR finalize + rowptr + dis ----------
__global__ __launch_bounds__(256) void k_fillC(const int* __restrict__ tmp,
                                               const int* __restrict__ bbase,
                                               int* __restrict__ rowptr,
                                               float* __restrict__ dis,
                                               int* __restrict__ esrc, int N) {
  __shared__ int cnt[NPB];
  __shared__ int loc[NPB];
  __shared__ int sh[256];
  int b = blockIdx.x, t = threadIdx.x;
  int beg = bbase[b], end = bbase[b + 1];
  int base_node = b << 9;
  cnt[t] = 0; cnt[t + 256] = 0;
  __syncthreads();
  for (int e = beg + t; e < end; e += 256)
    atomicAdd(&cnt[tmp[e] >> 17], 1);
  __syncthreads();
  int c0 = cnt[2 * t], c1 = cnt[2 * t + 1];
  sh[t] = c0 + c1;
  __syncthreads();
  for (int off = 1; off < 256; off <<= 1) {
    int x = 0;
    if (t >= off) x = sh[t - off];
    __syncthreads();
    if (t >= off) sh[t] += x;
    __syncthreads();
  }
  int pre = t ? sh[t - 1] : 0;
  loc[2 * t] = beg + pre;
  loc[2 * t + 1] = beg + pre + c0;
  int v0 = base_node + 2 * t, v1 = v0 + 1;
  if (v0 < N) { rowptr[v0] = beg + pre;      dis[v0] = rsqrtf((float)(c0 + 2)); }
  if (v1 < N) { rowptr[v1] = beg + pre + c0; dis[v1] = rsqrtf((float)(c1 + 2)); }
  __syncthreads();
  for (int e = beg + t; e < end; e += 256) {
    int u = tmp[e];
    int pos = atomicAdd(&loc[u >> 17], 1);
    esrc[pos] = u & 0x1FFFF;
  }
}

// ---------------- fp32 GEMM: C[M x BN] = A[M x 128] * W[128 x BN] ----------
// 256 threads, BM=128, thread tile 8 rows x (BN/64 groups of 4 cols).
// A is fp32 or fp16 (AHALF); C is written fp16.
template <int BN, bool AHALF>
__global__ __launch_bounds__(256) void k_gemm(const void* __restrict__ Av,
                                              const float* __restrict__ W,
                                              __half* __restrict__ C, int M) {
  constexpr int NG = BN / 64;
  __shared__ float As[16][132];  // transposed A tile: As[k][row], padded
  __shared__ float Ws[16][BN];
  int t = threadIdx.x;
  int tc = t & 15, tr = t >> 4;
  int row0 = blockIdx.x * 128;
  float acc[8][NG][4];
#pragma unroll
  for (int i = 0; i < 8; ++i)
#pragma unroll
    for (int g = 0; g < NG; ++g)
#pragma unroll
      for (int j = 0; j < 4; ++j) acc[i][g][j] = 0.f;

  for (int k0 = 0; k0 < 128; k0 += 16) {
#pragma unroll
    for (int i = 0; i < 2; ++i) {
      int idx = t * 2 + i;
      int r = idx >> 2, q = idx & 3;
      int gr = row0 + r;
      float4 v = make_float4(0.f, 0.f, 0.f, 0.f);
      if (gr < M) {
        if constexpr (AHALF) {
          const __half* A = (const __half*)Av;
          uint2 u = *(const uint2*)&A[(size_t)gr * 128 + k0 + q * 4];
          __half2 p0 = *(__half2*)&u.x, p1 = *(__half2*)&u.y;
          v = make_float4(__low2float(p0), __high2float(p0),
                          __low2float(p1), __high2float(p1));
        } else {
          v = *(const float4*)&((const float*)Av)[(size_t)gr * 128 + k0 + q * 4];
        }
      }
      As[q * 4 + 0][r] = v.x; As[q * 4 + 1][r] = v.y;
      As[q * 4 + 2][r] = v.z; As[q * 4 + 3][r] = v.w;
    }
#pragma unroll
    for (int i = 0; i < BN / 64; ++i) {
      int idx = t + i * 256;
      int k = idx / (BN / 4), c4 = idx % (BN / 4);
      *(float4*)&Ws[k][c4 * 4] = *(const float4*)&W[(long long)(k0 + k) * BN + c4 * 4];
    }
    __syncthreads();
#pragma unroll
    for (int k = 0; k < 16; ++k) {
      float a[8], bb[NG][4];
      *(float4*)&a[0] = *(const float4*)&As[k][tr * 8];
      *(float4*)&a[4] = *(const float4*)&As[k][tr * 8 + 4];
#pragma unroll
      for (int g = 0; g < NG; ++g)
        *(float4*)&bb[g][0] = *(const float4*)&Ws[k][g * 64 + tc * 4];
#pragma unroll
      for (int i = 0; i < 8; ++i)
#pragma unroll
        for (int g = 0; g < NG; ++g)
#pragma unroll
          for (int j = 0; j < 4; ++j)
            acc[i][g][j] = fmaf(a[i], bb[g][j], acc[i][g][j]);
    }
    __syncthreads();
  }
#pragma unroll
  for (int i = 0; i < 8; ++i) {
    int gr = row0 + tr * 8 + i;
    if (gr < M) {
#pragma unroll
      for (int g = 0; g < NG; ++g) {
        h4 hh;
        hh.a = __floats2half2_rn(acc[i][g][0], acc[i][g][1]);
        hh.b = __floats2half2_rn(acc[i][g][2], acc[i][g][3]);
        *(h4*)&C[(size_t)gr * BN + g * 64 + tc * 4] = hh;
      }
    }
  }
}

// ---------------- gather (A-hat propagate), one wave per node ----------------
// D=128, fp16 in, fp16 out (+bias, relu). Lane covers 2 features.
// norm recomputed as dis[src]*dis[v] (wave-uniform broadcast loads, L2-hot).
__global__ __launch_bounds__(256) void k_gather128(const __half* __restrict__ t,
    const float* __restrict__ bias, const int* __restrict__ rowptr,
    const int* __restrict__ esrc, const float* __restrict__ dis,
    __half* __restrict__ o, int n) {
  int gw = (int)((blockIdx.x * blockDim.x + threadIdx.x) >> 6);
  int lane = threadIdx.x & 63;
  int nw = (int)((gridDim.x * blockDim.x) >> 6);
  int f = lane * 2;
  float bb0 = bias[f], bb1 = bias[f + 1];
  for (int v = gw; v < n; v += nw) {
    float dv = dis[v];
    float s = 2.f * dv * dv;  // two self-loops, norm = dis^2 each
    __half2 xv = *(const __half2*)&t[(size_t)v * 128 + f];
    float a0 = s * __low2float(xv), a1 = s * __high2float(xv);
    int beg = rowptr[v], end = rowptr[v + 1];
    int e = beg;
    for (; e + 3 < end; e += 4) {
      int s0 = esrc[e], s1 = esrc[e + 1], s2 = esrc[e + 2], s3 = esrc[e + 3];
      float n0 = dis[s0] * dv, n1 = dis[s1] * dv;
      float n2 = dis[s2] * dv, n3 = dis[s3] * dv;
      __half2 x0 = *(const __half2*)&t[(size_t)s0 * 128 + f];
      __half2 x1 = *(const __half2*)&t[(size_t)s1 * 128 + f];
      __half2 x2 = *(const __half2*)&t[(size_t)s2 * 128 + f];
      __half2 x3 = *(const __half2*)&t[(size_t)s3 * 128 + f];
      a0 = fmaf(n0, __low2float(x0), a0); a1 = fmaf(n0, __high2float(x0), a1);
      a0 = fmaf(n1, __low2float(x1), a0); a1 = fmaf(n1, __high2float(x1), a1);
      a0 = fmaf(n2, __low2float(x2), a0); a1 = fmaf(n2, __high2float(x2), a1);
      a0 = fmaf(n3, __low2float(x3), a0); a1 = fmaf(n3, __high2float(x3), a1);
    }
    for (; e < end; ++e) {
      int s0 = esrc[e];
      float n0 = dis[s0] * dv;
      __half2 x0 = *(const __half2*)&t[(size_t)s0 * 128 + f];
      a0 = fmaf(n0, __low2float(x0), a0); a1 = fmaf(n0, __high2float(x0), a1);
    }
    a0 += bb0; a1 += bb1;
    a0 = fmaxf(a0, 0.f); a1 = fmaxf(a1, 0.f);  // layer 1 always relu
    *(__half2*)&o[(size_t)v * 128 + f] = __floats2half2_rn(a0, a1);
  }
}

// D=64, fp16 in, fp32 out (+bias, no relu). Lane covers 1 feature.
__global__ __launch_bounds__(256) void k_gather64(const __half* __restrict__ t,
    const float* __restrict__ bias, const int* __restrict__ rowptr,
    const int* __restrict__ esrc, const float* __restrict__ dis,
    float* __restrict__ o, int n) {
  int gw = (int)((blockIdx.x * blockDim.x + threadIdx.x) >> 6);
  int lane = threadIdx.x & 63;
  int nw = (int)((gridDim.x * blockDim.x) >> 6);
  int f = lane;
  float bb = bias[f];
  for (int v = gw; v < n; v += nw) {
    float dv = dis[v];
    float s = 2.f * dv * dv;
    float a0 = s * __half2float(t[(size_t)v * 64 + f]);
    int beg = rowptr[v], end = rowptr[v + 1];
    int e = beg;
    for (; e + 3 < end; e += 4) {
      int s0 = esrc[e], s1 = esrc[e + 1], s2 = esrc[e + 2], s3 = esrc[e + 3];
      float n0 = dis[s0] * dv, n1 = dis[s1] * dv;
      float n2 = dis[s2] * dv, n3 = dis[s3] * dv;
      float x0 = __half2float(t[(size_t)s0 * 64 + f]);
      float x1 = __half2float(t[(size_t)s1 * 64 + f]);
      float x2 = __half2float(t[(size_t)s2 * 64 + f]);
      float x3 = __half2float(t[(size_t)s3 * 64 + f]);
      a0 = fmaf(n0, x0, a0);
      a0 = fmaf(n1, x1, a0);
      a0 = fmaf(n2, x2, a0);
      a0 = fmaf(n3, x3, a0);
    }
    for (; e < end; ++e) {
      int s0 = esrc[e];
      a0 = fmaf(dis[s0] * dv, __half2float(t[(size_t)s0 * 64 + f]), a0);
    }
    o[(size_t)v * 64 + f] = a0 + bb;
  }
}

extern "C" void kernel_launch(void* const* d_in, const int* in_sizes, int n_in,
                              void* d_out, int out_size, void* d_ws, size_t ws_size,
                              hipStream_t stream) {
  const float* x  = (const float*)d_in[0];
  const void*  ei = d_in[1];
  const float* W1 = (const float*)d_in[2];
  const float* b1 = (const float*)d_in[3];
  const float* W2 = (const float*)d_in[4];
  const float* b2 = (const float*)d_in[5];
  const int N = in_sizes[0] / 128;
  const int E = in_sizes[1] / 2;
  float* out = (float*)d_out;
  const int nb = (N + NPB - 1) / NPB;  // 196 buckets for N=100000

  // workspace carve-up (~65 MB total)
  size_t off = 0;
  auto alloc = [&](size_t bytes) -> void* {
    void* p = (char*)d_ws + off;
    off += (bytes + 255) & ~(size_t)255;
    return p;
  };
  int*    flag   = (int*)alloc(4);
  int*    bcnt   = (int*)alloc(NBMAX * 4);
  int*    bbase  = (int*)alloc((NBMAX + 1) * 4);
  int*    bcur   = (int*)alloc(NBMAX * 4);
  int*    rowptr = (int*)alloc(((size_t)N + 1) * 4);
  float*  dis    = (float*)alloc((size_t)N * 4);
  int*    tmp    = (int*)alloc((size_t)E * 4);
  int*    esrc   = (int*)alloc((size_t)E * 4);
  __half* t1     = (__half*)alloc((size_t)N * 128 * 2);
  __half* z1     = (__half*)alloc((size_t)N * 128 * 2);
  __half* t2     = t1;  // t1 is dead once gather1 has produced z1

  int nchunks = (E + CHUNK - 1) / CHUNK;

  k_detect<<<1, 256, 0, stream>>>((const int*)ei, flag, bcnt, nb);
  k_bcount<<<1024, 256, 0, stream>>>(ei, flag, E, bcnt, nb);
  k_bscan<<<1, 256, 0, stream>>>(bcnt, bbase, bcur, rowptr, nb, N, E);
  k_fillB<<<nchunks, 256, 0, stream>>>(ei, flag, E, bcur, tmp, nb);
  k_fillC<<<nb, 256, 0, stream>>>(tmp, bbase, rowptr, dis, esrc, N);

  // layer 1: t1 = x @ W1 (fp16 out); z1 = relu(Ahat t1 + b1) (fp16)
  k_gemm<128, false><<<(N + 127) / 128, 256, 0, stream>>>(x, W1, t1, N);
  k_gather128<<<2048, 256, 0, stream>>>(t1, b1, rowptr, esrc, dis, z1, N);
  // layer 2: t2 = z1 @ W2 (fp16 out); out = Ahat t2 + b2 (fp32)
  k_gemm<64, true><<<(N + 127) / 128, 256, 0, stream>>>(z1, W2, t2, N);
  k_gather64<<<2048, 256, 0, stream>>>(t2, b2, rowptr, esrc, dis, out, N);
}

// Round 5
// 241.056 us; speedup vs baseline: 2.5199x; 1.2060x over previous
//
#include <hip/hip_runtime.h>
#include <hip/hip_fp16.h>

#define NPB   512   // nodes per bucket (2^9)
#define NBMAX 256   // max buckets (N <= 131072)
#define CHUNK 4096  // edges staged per block iteration in k_fillB

using f16x4 = __attribute__((ext_vector_type(4))) _Float16;
using f32x4 = __attribute__((ext_vector_type(4))) float;

// ---------------- edge-index dtype detection + bucket-count zeroing --------
// int64 node indices < 2^31 have zero high words (little-endian). For real
// int32 index data, 64 consecutive odd words all being zero is impossible.
__global__ void k_detect(const int* __restrict__ ei32, int* __restrict__ flag,
                         int* __restrict__ bcnt, int nb) {
  int t = threadIdx.x;
  if (t < nb) bcnt[t] = 0;
  if (t == 0) {
    int z = 1;
    for (int k = 0; k < 64; ++k)
      if (ei32[2 * k + 1] != 0) { z = 0; break; }
    flag[0] = z;  // 1 => int64, 0 => int32
  }
}

__device__ __forceinline__ int edge_at(const void* ei, int is64, long long pos) {
  return is64 ? (int)((const long long*)ei)[pos] : ((const int*)ei)[pos];
}

// ---------------- phase A: per-bucket edge counts ----------------
__global__ __launch_bounds__(256) void k_bcount(const void* __restrict__ ei,
                                                const int* __restrict__ flag,
                                                int E, int* __restrict__ bcnt, int nb) {
  __shared__ int cnt[NBMAX];
  int t = threadIdx.x;
  cnt[t] = 0;
  __syncthreads();
  int is64 = flag[0];
  int stride = gridDim.x * blockDim.x;
  for (int e = blockIdx.x * blockDim.x + t; e < E; e += stride) {
    int c = edge_at(ei, is64, (long long)E + e);
    atomicAdd(&cnt[c >> 9], 1);
  }
  __syncthreads();
  if (t < nb && cnt[t]) atomicAdd(&bcnt[t], cnt[t]);
}

// ---------------- scan bucket counts -> bucket bases + cursors -------------
__global__ void k_bscan(const int* __restrict__ bcnt, int* __restrict__ bbase,
                        int* __restrict__ bcur, int* __restrict__ rowptr,
                        int nb, int N, int E) {
  __shared__ int sh[NBMAX];
  int t = threadIdx.x;
  sh[t] = (t < nb) ? bcnt[t] : 0;
  __syncthreads();
  for (int off = 1; off < NBMAX; off <<= 1) {
    int x = 0;
    if (t >= off) x = sh[t - off];
    __syncthreads();
    if (t >= off) sh[t] += x;
    __syncthreads();
  }
  int excl = t ? sh[t - 1] : 0;
  if (t < nb) { bbase[t] = excl; bcur[t] = excl; }
  if (t == 0) { bbase[nb] = E; rowptr[N] = E; }
}

// ---------------- phase B: bucket-partition edges with write combining -----
__global__ __launch_bounds__(256) void k_fillB(const void* __restrict__ ei,
                                               const int* __restrict__ flag, int E,
                                               int* __restrict__ bcur,
                                               int* __restrict__ tmp, int nb) {
  __shared__ int cntL[NBMAX], startL[NBMAX], curL[NBMAX], gofs[NBMAX];
  __shared__ int sh[NBMAX];
  __shared__ int stage[CHUNK];
  __shared__ unsigned char sbkt[CHUNK];
  int t = threadIdx.x;
  int is64 = flag[0];
  for (long long base = (long long)blockIdx.x * CHUNK; base < E;
       base += (long long)gridDim.x * CHUNK) {
    int m = (int)min((long long)CHUNK, (long long)E - base);
    cntL[t] = 0;
    __syncthreads();
    for (int i = t; i < m; i += 256) {
      int c = edge_at(ei, is64, (long long)E + base + i);
      atomicAdd(&cntL[c >> 9], 1);
    }
    __syncthreads();
    sh[t] = cntL[t];
    __syncthreads();
    for (int off = 1; off < NBMAX; off <<= 1) {
      int x = 0;
      if (t >= off) x = sh[t - off];
      __syncthreads();
      if (t >= off) sh[t] += x;
      __syncthreads();
    }
    int excl = t ? sh[t - 1] : 0;
    startL[t] = excl;
    curL[t] = excl;
    if (t < nb && cntL[t] > 0) gofs[t] = atomicAdd(&bcur[t], cntL[t]);
    __syncthreads();
    for (int i = t; i < m; i += 256) {
      int r = edge_at(ei, is64, base + i);
      int c = edge_at(ei, is64, (long long)E + base + i);
      int b = c >> 9;
      int p = atomicAdd(&curL[b], 1);
      stage[p] = ((c & 511) << 17) | r;
      sbkt[p] = (unsigned char)b;
    }
    __syncthreads();
    for (int i = t; i < m; i += 256) {
      int b = sbkt[i];
      tmp[gofs[b] + (i - startL[b])] = stage[i];
    }
    __syncthreads();
  }
}

// ---------------- phase C: per-bucket CSR finalize + rowptr + dis ----------
__global__ __launch_bounds__(256) void k_fillC(const int* __restrict__ tmp,
                                               const int* __restrict__ bbase,
                                               int* __restrict__ rowptr,
                                               float* __restrict__ dis,
                                               int* __restrict__ esrc, int N) {
  __shared__ int cnt[NPB];
  __shared__ int loc[NPB];
  __shared__ int sh[256];
  int b = blockIdx.x, t = threadIdx.x;
  int beg = bbase[b], end = bbase[b + 1];
  int base_node = b << 9;
  cnt[t] = 0; cnt[t + 256] = 0;
  __syncthreads();
  for (int e = beg + t; e < end; e += 256)
    atomicAdd(&cnt[tmp[e] >> 17], 1);
  __syncthreads();
  int c0 = cnt[2 * t], c1 = cnt[2 * t + 1];
  sh[t] = c0 + c1;
  __syncthreads();
  for (int off = 1; off < 256; off <<= 1) {
    int x = 0;
    if (t >= off) x = sh[t - off];
    __syncthreads();
    if (t >= off) sh[t] += x;
    __syncthreads();
  }
  int pre = t ? sh[t - 1] : 0;
  loc[2 * t] = beg + pre;
  loc[2 * t + 1] = beg + pre + c0;
  int v0 = base_node + 2 * t, v1 = v0 + 1;
  if (v0 < N) { rowptr[v0] = beg + pre;      dis[v0] = rsqrtf((float)(c0 + 2)); }
  if (v1 < N) { rowptr[v1] = beg + pre + c0; dis[v1] = rsqrtf((float)(c1 + 2)); }
  __syncthreads();
  for (int e = beg + t; e < end; e += 256) {
    int u = tmp[e];
    int pos = atomicAdd(&loc[u >> 17], 1);
    esrc[pos] = u & 0x1FFFF;
  }
}

// ---------------- MFMA GEMM: C[M x BN](fp16) = A[M x 128] * W[128 x BN] ----
// 256 threads = 4 waves. Block tile 64 x BN, grid-stride over row tiles.
// W staged transposed in LDS (fp16) once per block. mfma_f32_16x16x16f16:
// A frag: row=lane&15, k=(lane>>4)*4+i ; B frag: col=lane&15, same k;
// D frag: col=lane&15, row=(lane>>4)*4+reg  (CDNA blog + guide m89 family).
template <int BN, bool AHALF>
__global__ __launch_bounds__(256) void k_gemm_mfma(const void* __restrict__ Av,
                                                   const float* __restrict__ W,
                                                   __half* __restrict__ C,
                                                   int M, int tiles) {
  __shared__ _Float16 Wt[BN][136];   // W transposed [col][k], pad to 272 B stride
  __shared__ _Float16 At[64][136];   // A tile [row][k]; reused for C staging
  constexpr int NT = BN / 64;        // col-tiles per wave (128->2, 64->1)
  constexpr int CH = BN / 4;         // 4-wide chunks per row
  int t = threadIdx.x;
  int lane = t & 63, w = t >> 6;
  int lrow = lane & 15;
  int kq = (lane >> 4) * 4;          // k offset within 16-step
  int wcol0 = w * (BN / 4);

  // stage W transposed (once per block)
  for (int idx = t; idx < 128 * BN / 4; idx += 256) {
    int k = idx / CH, c4 = (idx % CH) * 4;
    float4 v = *(const float4*)&W[(size_t)k * BN + c4];
    Wt[c4 + 0][k] = (_Float16)v.x;
    Wt[c4 + 1][k] = (_Float16)v.y;
    Wt[c4 + 2][k] = (_Float16)v.z;
    Wt[c4 + 3][k] = (_Float16)v.w;
  }

  for (int tile = blockIdx.x; tile < tiles; tile += gridDim.x) {
    int row0 = tile * 64;
    __syncthreads();  // At free (also orders Wt staging on first iter)
    // stage A tile: 64 rows x 128 k, fp16
#pragma unroll
    for (int i = 0; i < 8; ++i) {
      int idx = t + i * 256;
      int r = idx >> 5, c = (idx & 31) * 4;
      int gr = row0 + r;
      f16x4 hv = {0, 0, 0, 0};
      if (gr < M) {
        if constexpr (AHALF) {
          hv = *(const f16x4*)&((const _Float16*)Av)[(size_t)gr * 128 + c];
        } else {
          float4 v = *(const float4*)&((const float*)Av)[(size_t)gr * 128 + c];
          hv = f16x4{(_Float16)v.x, (_Float16)v.y, (_Float16)v.z, (_Float16)v.w};
        }
      }
      *(f16x4*)&At[r][c] = hv;
    }
    __syncthreads();
    // compute: wave w -> rows 0..63, cols wcol0..wcol0+NT*16-1
    f32x4 acc[4][NT];
#pragma unroll
    for (int mt = 0; mt < 4; ++mt)
#pragma unroll
      for (int nt = 0; nt < NT; ++nt) acc[mt][nt] = f32x4{0.f, 0.f, 0.f, 0.f};
#pragma unroll
    for (int k0 = 0; k0 < 128; k0 += 16) {
      int kk = k0 + kq;
      f16x4 a[4], b[NT];
#pragma unroll
      for (int mt = 0; mt < 4; ++mt)
        a[mt] = *(const f16x4*)&At[mt * 16 + lrow][kk];
#pragma unroll
      for (int nt = 0; nt < NT; ++nt)
        b[nt] = *(const f16x4*)&Wt[wcol0 + nt * 16 + lrow][kk];
#pragma unroll
      for (int mt = 0; mt < 4; ++mt)
#pragma unroll
        for (int nt = 0; nt < NT; ++nt)
          acc[mt][nt] = __builtin_amdgcn_mfma_f32_16x16x16f16(a[mt], b[nt],
                                                              acc[mt][nt], 0, 0, 0);
    }
    __syncthreads();  // all waves done reading At
    // stage C tile into At (as [row][col])
#pragma unroll
    for (int mt = 0; mt < 4; ++mt)
#pragma unroll
      for (int nt = 0; nt < NT; ++nt) {
        int cc = wcol0 + nt * 16 + lrow;
        int rr = mt * 16 + kq;
#pragma unroll
        for (int reg = 0; reg < 4; ++reg)
          At[rr + reg][cc] = (_Float16)acc[mt][nt][reg];
      }
    __syncthreads();
    // coalesced global store, 8 B per thread-chunk
#pragma unroll
    for (int i = 0; i < BN / 16; ++i) {
      int idx = t + i * 256;
      int r = idx / CH, c = (idx % CH) * 4;
      int gr = row0 + r;
      if (gr < M)
        *(f16x4*)&C[(size_t)gr * BN + c] = *(const f16x4*)&At[r][c];
    }
  }
}

// ---------------- gather 128 (A-hat propagate), 2 half-waves per node ------
// Each half-wave covers a full 256 B row: 32 lanes x uint2 (4 features).
__global__ __launch_bounds__(256) void k_gather128(const __half* __restrict__ t,
    const float* __restrict__ bias, const int* __restrict__ rowptr,
    const int* __restrict__ esrc, const float* __restrict__ dis,
    __half* __restrict__ o, int n) {
  int gw = (int)((blockIdx.x * blockDim.x + threadIdx.x) >> 6);
  int lane = threadIdx.x & 63;
  int nw = (int)((gridDim.x * blockDim.x) >> 6);
  int half = lane >> 5;
  int f = (lane & 31) * 4;
  for (int v = gw; v < n; v += nw) {
    float dv = dis[v];
    float a0 = 0.f, a1 = 0.f, a2 = 0.f, a3 = 0.f;
    int beg = rowptr[v], end = rowptr[v + 1];
    int e = beg + half;
    for (; e + 6 < end; e += 8) {
      int s0 = esrc[e], s1 = esrc[e + 2], s2 = esrc[e + 4], s3 = esrc[e + 6];
      float n0 = dis[s0] * dv, n1 = dis[s1] * dv;
      float n2 = dis[s2] * dv, n3 = dis[s3] * dv;
      uint2 u0 = *(const uint2*)&t[(size_t)s0 * 128 + f];
      uint2 u1 = *(const uint2*)&t[(size_t)s1 * 128 + f];
      uint2 u2 = *(const uint2*)&t[(size_t)s2 * 128 + f];
      uint2 u3 = *(const uint2*)&t[(size_t)s3 * 128 + f];
      __half2 p;
      p = *(__half2*)&u0.x; a0 = fmaf(n0, __low2float(p), a0); a1 = fmaf(n0, __high2float(p), a1);
      p = *(__half2*)&u0.y; a2 = fmaf(n0, __low2float(p), a2); a3 = fmaf(n0, __high2float(p), a3);
      p = *(__half2*)&u1.x; a0 = fmaf(n1, __low2float(p), a0); a1 = fmaf(n1, __high2float(p), a1);
      p = *(__half2*)&u1.y; a2 = fmaf(n1, __low2float(p), a2); a3 = fmaf(n1, __high2float(p), a3);
      p = *(__half2*)&u2.x; a0 = fmaf(n2, __low2float(p), a0); a1 = fmaf(n2, __high2float(p), a1);
      p = *(__half2*)&u2.y; a2 = fmaf(n2, __low2float(p), a2); a3 = fmaf(n2, __high2float(p), a3);
      p = *(__half2*)&u3.x; a0 = fmaf(n3, __low2float(p), a0); a1 = fmaf(n3, __high2float(p), a1);
      p = *(__half2*)&u3.y; a2 = fmaf(n3, __low2float(p), a2); a3 = fmaf(n3, __high2float(p), a3);
    }
    for (; e < end; e += 2) {
      int s0 = esrc[e];
      float n0 = dis[s0] * dv;
      uint2 u0 = *(const uint2*)&t[(size_t)s0 * 128 + f];
      __half2 p;
      p = *(__half2*)&u0.x; a0 = fmaf(n0, __low2float(p), a0); a1 = fmaf(n0, __high2float(p), a1);
      p = *(__half2*)&u0.y; a2 = fmaf(n0, __low2float(p), a2); a3 = fmaf(n0, __high2float(p), a3);
    }
    if (half == 0) {  // self term (two self-loops)
      float s = 2.f * dv * dv;
      uint2 uv = *(const uint2*)&t[(size_t)v * 128 + f];
      __half2 p;
      p = *(__half2*)&uv.x; a0 = fmaf(s, __low2float(p), a0); a1 = fmaf(s, __high2float(p), a1);
      p = *(__half2*)&uv.y; a2 = fmaf(s, __low2float(p), a2); a3 = fmaf(s, __high2float(p), a3);
    }
    a0 += __shfl_xor(a0, 32); a1 += __shfl_xor(a1, 32);
    a2 += __shfl_xor(a2, 32); a3 += __shfl_xor(a3, 32);
    if (half == 0) {
      a0 = fmaxf(a0 + bias[f], 0.f);
      a1 = fmaxf(a1 + bias[f + 1], 0.f);
      a2 = fmaxf(a2 + bias[f + 2], 0.f);
      a3 = fmaxf(a3 + bias[f + 3], 0.f);
      __half2 h0 = __floats2half2_rn(a0, a1), h1 = __floats2half2_rn(a2, a3);
      uint2 uu;
      uu.x = *(unsigned int*)&h0; uu.y = *(unsigned int*)&h1;
      *(uint2*)&o[(size_t)v * 128 + f] = uu;
    }
  }
}

// ---------------- gather 64, 4 quarter-wave groups per node ----------------
// Each 16-lane group covers a full 128 B row: 16 lanes x uint2 (4 features).
__global__ __launch_bounds__(256) void k_gather64(const __half* __restrict__ t,
    const float* __restrict__ bias, const int* __restrict__ rowptr,
    const int* __restrict__ esrc, const float* __restrict__ dis,
    float* __restrict__ o, int n) {
  int gw = (int)((blockIdx.x * blockDim.x + threadIdx.x) >> 6);
  int lane = threadIdx.x & 63;
  int nw = (int)((gridDim.x * blockDim.x) >> 6);
  int sub = lane >> 4;
  int f = (lane & 15) * 4;
  for (int v = gw; v < n; v += nw) {
    float dv = dis[v];
    float a0 = 0.f, a1 = 0.f, a2 = 0.f, a3 = 0.f;
    int beg = rowptr[v], end = rowptr[v + 1];
    int e = beg + sub;
    for (; e + 7 < end; e += 8) {
      int s0 = esrc[e], s1 = esrc[e + 4];
      float n0 = dis[s0] * dv, n1 = dis[s1] * dv;
      uint2 u0 = *(const uint2*)&t[(size_t)s0 * 64 + f];
      uint2 u1 = *(const uint2*)&t[(size_t)s1 * 64 + f];
      __half2 p;
      p = *(__half2*)&u0.x; a0 = fmaf(n0, __low2float(p), a0); a1 = fmaf(n0, __high2float(p), a1);
      p = *(__half2*)&u0.y; a2 = fmaf(n0, __low2float(p), a2); a3 = fmaf(n0, __high2float(p), a3);
      p = *(__half2*)&u1.x; a0 = fmaf(n1, __low2float(p), a0); a1 = fmaf(n1, __high2float(p), a1);
      p = *(__half2*)&u1.y; a2 = fmaf(n1, __low2float(p), a2); a3 = fmaf(n1, __high2float(p), a3);
    }
    for (; e < end; e += 4) {
      int s0 = esrc[e];
      float n0 = dis[s0] * dv;
      uint2 u0 = *(const uint2*)&t[(size_t)s0 * 64 + f];
      __half2 p;
      p = *(__half2*)&u0.x; a0 = fmaf(n0, __low2float(p), a0); a1 = fmaf(n0, __high2float(p), a1);
      p = *(__half2*)&u0.y; a2 = fmaf(n0, __low2float(p), a2); a3 = fmaf(n0, __high2float(p), a3);
    }
    if (sub == 0) {  // self term
      float s = 2.f * dv * dv;
      uint2 uv = *(const uint2*)&t[(size_t)v * 64 + f];
      __half2 p;
      p = *(__half2*)&uv.x; a0 = fmaf(s, __low2float(p), a0); a1 = fmaf(s, __high2float(p), a1);
      p = *(__half2*)&uv.y; a2 = fmaf(s, __low2float(p), a2); a3 = fmaf(s, __high2float(p), a3);
    }
    a0 += __shfl_xor(a0, 16); a0 += __shfl_xor(a0, 32);
    a1 += __shfl_xor(a1, 16); a1 += __shfl_xor(a1, 32);
    a2 += __shfl_xor(a2, 16); a2 += __shfl_xor(a2, 32);
    a3 += __shfl_xor(a3, 16); a3 += __shfl_xor(a3, 32);
    if (sub == 0) {
      float4 r;
      r.x = a0 + bias[f];     r.y = a1 + bias[f + 1];
      r.z = a2 + bias[f + 2]; r.w = a3 + bias[f + 3];
      *(float4*)&o[(size_t)v * 64 + f] = r;
    }
  }
}

extern "C" void kernel_launch(void* const* d_in, const int* in_sizes, int n_in,
                              void* d_out, int out_size, void* d_ws, size_t ws_size,
                              hipStream_t stream) {
  const float* x  = (const float*)d_in[0];
  const void*  ei = d_in[1];
  const float* W1 = (const float*)d_in[2];
  const float* b1 = (const float*)d_in[3];
  const float* W2 = (const float*)d_in[4];
  const float* b2 = (const float*)d_in[5];
  const int N = in_sizes[0] / 128;
  const int E = in_sizes[1] / 2;
  float* out = (float*)d_out;
  const int nb = (N + NPB - 1) / NPB;

  size_t off = 0;
  auto alloc = [&](size_t bytes) -> void* {
    void* p = (char*)d_ws + off;
    off += (bytes + 255) & ~(size_t)255;
    return p;
  };
  int*    flag   = (int*)alloc(4);
  int*    bcnt   = (int*)alloc(NBMAX * 4);
  int*    bbase  = (int*)alloc((NBMAX + 1) * 4);
  int*    bcur   = (int*)alloc(NBMAX * 4);
  int*    rowptr = (int*)alloc(((size_t)N + 1) * 4);
  float*  dis    = (float*)alloc((size_t)N * 4);
  int*    tmp    = (int*)alloc((size_t)E * 4);
  int*    esrc   = (int*)alloc((size_t)E * 4);
  __half* t1     = (__half*)alloc((size_t)N * 128 * 2);
  __half* z1     = (__half*)alloc((size_t)N * 128 * 2);
  __half* t2     = t1;  // t1 dead once gather1 produced z1

  int nchunks = (E + CHUNK - 1) / CHUNK;
  int tiles = (N + 63) / 64;

  k_detect<<<1, 256, 0, stream>>>((const int*)ei, flag, bcnt, nb);
  k_bcount<<<1024, 256, 0, stream>>>(ei, flag, E, bcnt, nb);
  k_bscan<<<1, 256, 0, stream>>>(bcnt, bbase, bcur, rowptr, nb, N, E);
  k_fillB<<<nchunks, 256, 0, stream>>>(ei, flag, E, bcur, tmp, nb);
  k_fillC<<<nb, 256, 0, stream>>>(tmp, bbase, rowptr, dis, esrc, N);

  // layer 1: t1 = x @ W1 (fp16); z1 = relu(Ahat t1 + b1) (fp16)
  k_gemm_mfma<128, false><<<min(tiles, 768), 256, 0, stream>>>(x, W1, t1, N, tiles);
  k_gather128<<<2048, 256, 0, stream>>>(t1, b1, rowptr, esrc, dis, z1, N);
  // layer 2: t2 = z1 @ W2 (fp16); out = Ahat t2 + b2 (fp32)
  k_gemm_mfma<64, true><<<min(tiles, 768), 256, 0, stream>>>(z1, W2, t2, N, tiles);
  k_gather64<<<2048, 256, 0, stream>>>(t2, b2, rowptr, esrc, dis, out, N);
}